// Round 7
// baseline (155.002 us; speedup 1.0000x reference)
//
#include <hip/hip_runtime.h>
#include <hip/hip_fp16.h>

#define NW 20

// splat coefficient set (7 packed splats) for one wire's fused RY*RX unitary
// U = [[a+id, -e-if],[e-if, a-id]]
struct PkW7 { __half2 a, d, dn, e, en, f, fn, pad; };   // 32 B

__device__ __forceinline__ __half2 pkrtz(float lo, float hi) {
    typedef __fp16 f16x2 __attribute__((ext_vector_type(2)));
    f16x2 v = __builtin_amdgcn_cvt_pkrtz(lo, hi);
    return *reinterpret_cast<__half2*>(&v);
}
__device__ __forceinline__ unsigned h2u(__half2 v) { return *reinterpret_cast<unsigned*>(&v); }
__device__ __forceinline__ __half2 u2h(unsigned v) { return *reinterpret_cast<__half2*>(&v); }

// SoA packed butterfly on 8 regs/component: re/im in separate half2,
// each half2 = 2 batch states. Pure element-wise pk ops.
template<int JB>
__device__ __forceinline__ void stage8s(__half2 (&xr)[8], __half2 (&xi)[8], const PkW7 u) {
    #pragma unroll
    for (int base = 0; base < 8; ++base)
        if (!(base & (1 << JB))) {
            const int p = base | (1 << JB);
            __half2 x0r = xr[base], x0i = xi[base], x1r = xr[p], x1i = xi[p];
            xr[base] = __hfma2(u.a, x0r, __hfma2(u.dn, x0i, __hfma2(u.en, x1r, __hmul2(u.f , x1i))));
            xi[base] = __hfma2(u.a, x0i, __hfma2(u.d , x0r, __hfma2(u.en, x1i, __hmul2(u.fn, x1r))));
            xr[p]    = __hfma2(u.e, x0r, __hfma2(u.f , x0i, __hfma2(u.a , x1r, __hmul2(u.d , x1i))));
            xi[p]    = __hfma2(u.e, x0i, __hfma2(u.fn, x0r, __hfma2(u.a , x1i, __hmul2(u.dn, x1r))));
        }
}

// cbuf layout: [0..3] = wire19 f32 (a,d,e,f)*1024 ; then PkW7[20] at cbuf+4
__global__ void setupk(const float* __restrict__ params, float* __restrict__ cbuf) {
    int w = threadIdx.x;
    if (w < NW) {
        double s1, c1, s2, c2;
        sincos(0.5 * (double)params[w],      &s1, &c1);   // RX
        sincos(0.5 * (double)params[w + NW], &s2, &c2);   // RY
        float a = (float)(c1 * c2), d = (float)(s1 * s2);
        float e = (float)(s2 * c1), f = (float)(c2 * s1);
        if (w == 19) {   // first pass1 stage stays f32 and carries the x1024 scale
            cbuf[0] = a * 1024.f; cbuf[1] = d * 1024.f;
            cbuf[2] = e * 1024.f; cbuf[3] = f * 1024.f;
        }
        PkW7 pw;
        pw.a  = __floats2half2_rn( a,  a);
        pw.d  = __floats2half2_rn( d,  d);
        pw.dn = __floats2half2_rn(-d, -d);
        pw.e  = __floats2half2_rn( e,  e);
        pw.en = __floats2half2_rn(-e, -e);
        pw.f  = __floats2half2_rn( f,  f);
        pw.fn = __floats2half2_rn(-f, -f);
        pw.pad = __floats2half2_rn(0.f, 0.f);
        ((PkW7*)(cbuf + 4))[w] = pw;
    }
}

// ---------------------------------------------------------------------------
// Pass 1: wires 9..19 (low bits 0..10). Block = 2048 amps x 2 batches
// (pr, pr+16) packed in half2 lanes. 16.9 KiB LDS -> 8 blocks/CU.
// 4 rounds: bits {0(f32),1,10} | {2,3,4} | {5,6,7} | {8,9}.
// Skew SK(i)=i+(i>>5) folded to compile-time immediates.
// ---------------------------------------------------------------------------
__global__ __launch_bounds__(256, 8) void pass1(const float* __restrict__ state,
                                                const float* __restrict__ cbuf,
                                                uint2* __restrict__ amp) {
    __shared__ __half2 Lr[2112];
    __shared__ __half2 Li[2112];
    const int t     = threadIdx.x;
    const int pr    = blockIdx.x >> 9;      // batch pair (pr, pr+16)
    const int chunk = blockIdx.x & 511;     // h9 = y bits 11..19
    const PkW7* PW = (const PkW7*)(cbuf + 4);
    const float a19 = cbuf[0], d19 = cbuf[1], e19 = cbuf[2], f19 = cbuf[3];

    const float4* s0 = (const float4*)(state + ((size_t)pr << 20) + ((size_t)chunk << 11));
    const float4* s1 = (const float4*)((const float*)s0 + ((size_t)16 << 20));

    __half2 xr[8], xi[8];
    // Round 1: reg r = m + 4k owns p-bits {0,1,10}; wires 19 (f32), 18, 9
    #pragma unroll
    for (int k = 0; k < 2; ++k) {           // p = 4t + m + 1024k (coalesced)
        float4 v0 = s0[k * 256 + t];
        float4 v1 = s1[k * 256 + t];
        float r0a = fmaf(a19, v0.x, -e19 * v0.y), i0a = fmaf( d19, v0.x, -f19 * v0.y);
        float r1a = fmaf(e19, v0.x,  a19 * v0.y), i1a = fmaf(-f19, v0.x, -d19 * v0.y);
        float r0b = fmaf(a19, v1.x, -e19 * v1.y), i0b = fmaf( d19, v1.x, -f19 * v1.y);
        float r1b = fmaf(e19, v1.x,  a19 * v1.y), i1b = fmaf(-f19, v1.x, -d19 * v1.y);
        xr[4*k+0] = pkrtz(r0a, r0b); xi[4*k+0] = pkrtz(i0a, i0b);
        xr[4*k+1] = pkrtz(r1a, r1b); xi[4*k+1] = pkrtz(i1a, i1b);
        r0a = fmaf(a19, v0.z, -e19 * v0.w); i0a = fmaf( d19, v0.z, -f19 * v0.w);
        r1a = fmaf(e19, v0.z,  a19 * v0.w); i1a = fmaf(-f19, v0.z, -d19 * v0.w);
        r0b = fmaf(a19, v1.z, -e19 * v1.w); i0b = fmaf( d19, v1.z, -f19 * v1.w);
        r1b = fmaf(e19, v1.z,  a19 * v1.w); i1b = fmaf(-f19, v1.z, -d19 * v1.w);
        xr[4*k+2] = pkrtz(r0a, r0b); xi[4*k+2] = pkrtz(i0a, i0b);
        xr[4*k+3] = pkrtz(r1a, r1b); xi[4*k+3] = pkrtz(i1a, i1b);
    }
    stage8s<1>(xr, xi, PW[18]);             // p-bit 1 -> wire 18
    stage8s<2>(xr, xi, PW[9]);              // p-bit 10 -> wire 9
    {   // write p = (r&3) + 4t + 1024(r>>2); SK -> p1 + (r&3) + 1056(r>>2)
        const int p1 = 4 * t + (t >> 3);
        #pragma unroll
        for (int r = 0; r < 8; ++r) {
            const int a = p1 + (r & 3) + 1056 * (r >> 2);
            Lr[a] = xr[r]; Li[a] = xi[r];
        }
    }
    __syncthreads();

    // Round 2: own p-bits {2,3,4} -> wires 17,16,15
    // p = (t&3) + 4r + 32(t>>2); SK -> q2 + 4r
    const int q2 = (t & 3) + 33 * (t >> 2);
    #pragma unroll
    for (int r = 0; r < 8; ++r) { xr[r] = Lr[q2 + 4*r]; xi[r] = Li[q2 + 4*r]; }
    stage8s<0>(xr, xi, PW[17]);
    stage8s<1>(xr, xi, PW[16]);
    stage8s<2>(xr, xi, PW[15]);
    #pragma unroll
    for (int r = 0; r < 8; ++r) { Lr[q2 + 4*r] = xr[r]; Li[q2 + 4*r] = xi[r]; }
    __syncthreads();

    // Round 3: own p-bits {5,6,7} -> wires 14,13,12
    // p = (t&31) + 32r + 256(t>>5); SK -> q3 + 33r
    const int q3 = (t & 31) + 264 * (t >> 5);
    #pragma unroll
    for (int r = 0; r < 8; ++r) { xr[r] = Lr[q3 + 33*r]; xi[r] = Li[q3 + 33*r]; }
    stage8s<0>(xr, xi, PW[14]);
    stage8s<1>(xr, xi, PW[13]);
    stage8s<2>(xr, xi, PW[12]);
    #pragma unroll
    for (int r = 0; r < 8; ++r) { Lr[q3 + 33*r] = xr[r]; Li[q3 + 33*r] = xi[r]; }
    __syncthreads();

    // Round 4: own p-bits {8,9,10} -> stages on bits 8,9 (wires 11,10)
    // p = t + 256r; SK -> q4 + 264r
    const int q4 = t + (t >> 5);
    #pragma unroll
    for (int r = 0; r < 8; ++r) { xr[r] = Lr[q4 + 264*r]; xi[r] = Li[q4 + 264*r]; }
    stage8s<0>(xr, xi, PW[11]);
    stage8s<1>(xr, xi, PW[10]);

    uint2* dst = amp + ((((size_t)pr << 9) | (size_t)chunk) << 11);
    #pragma unroll
    for (int r = 0; r < 8; ++r) {           // p = t + 256r: coalesced 512B/instr
        uint2 w; w.x = h2u(xr[r]); w.y = h2u(xi[r]);
        dst[t + 256 * r] = w;
    }
}

// ---------------------------------------------------------------------------
// Pass 2: wires 0..8 (h = y bits 11..19) + fused |psi|^2 * g(y) reduction.
// Block = 512 h x 4 low x 2 batches. g(y) = A(h) + sigma(h)*B(low).
// 3 rounds: h bits {0,1,2} | {3,4,5} | {6,7,8}. ~19 KiB LDS -> 8 blocks/CU.
// ---------------------------------------------------------------------------
__global__ __launch_bounds__(256, 8) void pass2(const uint2* __restrict__ amp,
                                                const float* __restrict__ cbuf,
                                                const float* __restrict__ Wv,
                                                float* __restrict__ pws) {
    __shared__ __half2 Lr[2112];
    __shared__ __half2 Li[2112];
    __shared__ float   Atab[512];
    __shared__ float   Btab[4];
    __shared__ float   wred[8];
    const int t  = threadIdx.x;
    const int pr = blockIdx.x >> 9;
    const int cb = blockIdx.x & 511;        // low-chunk: low = 4cb + l
    const PkW7* PW = (const PkW7*)(cbuf + 4);

    #pragma unroll
    for (int hh = t; hh < 512; hh += 256) { // A(h) = sum_{i<9} W_i*(-1)^par(h>>(8-i))
        float A = 0.f;
        #pragma unroll
        for (int i = 0; i < 9; ++i)
            A += Wv[i] * (1.f - 2.f * (float)(__popc(hh >> (8 - i)) & 1));
        Atab[hh] = A;
    }
    if (t < 4) {    // B(low) = sum_{i=9..19} W_i*(-1)^par(low>>(19-i))
        int low = cb * 4 + t;
        float Bs = 0.f;
        #pragma unroll
        for (int i = 9; i < 20; ++i)
            Bs += Wv[i] * (1.f - 2.f * (float)(__popc(low >> (19 - i)) & 1));
        Btab[t] = Bs;
    }

    // load: h = r + 8*(t>>2), l = t&3 ; addr = pr*2^20 + h*2048 + 4cb + l
    const uint2* src = amp + ((size_t)pr << 20) + ((size_t)(t >> 2) << 14) + (cb << 2) + (t & 3);
    __half2 xr[8], xi[8];
    #pragma unroll
    for (int r = 0; r < 8; ++r) {
        uint2 w = src[r << 11];
        xr[r] = u2h(w.x); xi[r] = u2h(w.y);
    }
    // Round 1: h bits {0,1,2} -> wires 8,7,6
    stage8s<0>(xr, xi, PW[8]);
    stage8s<1>(xr, xi, PW[7]);
    stage8s<2>(xr, xi, PW[6]);
    {   // write idx = l + 4r + 32(t>>2); SK -> w1 + 4r
        const int w1 = (t & 3) + 33 * (t >> 2);
        #pragma unroll
        for (int r = 0; r < 8; ++r) { Lr[w1 + 4*r] = xr[r]; Li[w1 + 4*r] = xi[r]; }
    }
    __syncthreads();                        // also covers Atab/Btab visibility

    // Round 2: own idx bits {5,6,7} = h bits {3,4,5} -> wires 5,4,3
    // idx = (t&31) + 32r + 256(t>>5); SK -> q2 + 33r
    const int q2 = (t & 31) + 264 * (t >> 5);
    #pragma unroll
    for (int r = 0; r < 8; ++r) { xr[r] = Lr[q2 + 33*r]; xi[r] = Li[q2 + 33*r]; }
    stage8s<0>(xr, xi, PW[5]);
    stage8s<1>(xr, xi, PW[4]);
    stage8s<2>(xr, xi, PW[3]);
    #pragma unroll
    for (int r = 0; r < 8; ++r) { Lr[q2 + 33*r] = xr[r]; Li[q2 + 33*r] = xi[r]; }
    __syncthreads();

    // Round 3: own idx bits {8,9,10} = h bits {6,7,8} -> wires 2,1,0
    // idx = t + 256r; SK -> q3 + 264r
    const int q3 = t + (t >> 5);
    #pragma unroll
    for (int r = 0; r < 8; ++r) { xr[r] = Lr[q3 + 264*r]; xi[r] = Li[q3 + 264*r]; }
    stage8s<0>(xr, xi, PW[2]);
    stage8s<1>(xr, xi, PW[1]);
    stage8s<2>(xr, xi, PW[0]);

    // fused weighted-probability accumulation: h = (t>>2) + 64r, l = t&3
    const float Bl = Btab[t & 3];
    float acc0 = 0.f, acc1 = 0.f;
    #pragma unroll
    for (int r = 0; r < 8; ++r) {
        const int h = (t >> 2) + 64 * r;
        const float sg = 1.f - 2.f * (float)(__popc(h) & 1);
        const float g  = fmaf(sg, Bl, Atab[h]);
        float2 vr = __half22float2(xr[r]);
        float2 vi = __half22float2(xi[r]);
        acc0 = fmaf(fmaf(vr.x, vr.x, vi.x * vi.x), g, acc0);
        acc1 = fmaf(fmaf(vr.y, vr.y, vi.y * vi.y), g, acc1);
    }
    #pragma unroll
    for (int off = 32; off > 0; off >>= 1) {
        acc0 += __shfl_down(acc0, off, 64);
        acc1 += __shfl_down(acc1, off, 64);
    }
    if ((t & 63) == 0) { wred[(t >> 6) * 2] = acc0; wred[(t >> 6) * 2 + 1] = acc1; }
    __syncthreads();
    if (t < 2)
        pws[blockIdx.x * 2 + t] = (wred[t] + wred[2 + t]) + (wred[4 + t] + wred[6 + t]);
}

// ---------------------------------------------------------------------------
// Final: deterministic reduction of 512 partials per batch, undo 2^20 scale.
// Batch b -> pair pr=b&15, slot sl=b>>4; partial index (pr*512+cb)*2+sl.
// ---------------------------------------------------------------------------
__global__ void finalk(const float* __restrict__ pws, const float* __restrict__ bias,
                       float* __restrict__ out) {
    const int t = threadIdx.x;
    const int b = t >> 3, j = t & 7;
    const int pr = b & 15, sl = b >> 4;
    float s = 0.f;
    #pragma unroll 4
    for (int k = 0; k < 64; ++k) {
        const int cb = j * 64 + k;
        s += pws[(pr * 512 + cb) * 2 + sl];
    }
    s += __shfl_down(s, 4, 8);
    s += __shfl_down(s, 2, 8);
    s += __shfl_down(s, 1, 8);
    if (j == 0) out[b] = s * (1.f / 1048576.f) + bias[0];
}

extern "C" void kernel_launch(void* const* d_in, const int* in_sizes, int n_in,
                              void* d_out, int out_size, void* d_ws, size_t ws_size,
                              hipStream_t stream) {
    const float* state  = (const float*)d_in[0];   // (32, 2^20) f32
    const float* params = (const float*)d_in[1];   // (40,) f32
    const float* Wv     = (const float*)d_in[2];   // (1,20) f32
    const float* bias   = (const float*)d_in[3];   // (1,)  f32
    float* out = (float*)d_out;                    // (32,) f32

    const size_t AMPB = (size_t)16 * (1u << 20) * 8;   // 128 MiB intermediate
    uint2* amp  = (uint2*)d_ws;
    float* pws  = (float*)((char*)d_ws + AMPB);        // 8192*2 floats = 64 KiB
    float* cbuf = (float*)((char*)d_ws + AMPB + 65536);

    setupk<<<1, 64, 0, stream>>>(params, cbuf);
    pass1 <<<16 * 512, 256, 0, stream>>>(state, cbuf, amp);
    pass2 <<<16 * 512, 256, 0, stream>>>(amp, cbuf, Wv, pws);
    finalk<<<1, 256, 0, stream>>>(pws, bias, out);
}

// Round 8
// 106.558 us; speedup vs baseline: 1.4546x; 1.4546x over previous
//
#include <hip/hip_runtime.h>
#include <hip/hip_fp16.h>

#define NW 20

// splat coefficient set (7 packed splats) for one wire's fused RY*RX unitary
// U = [[a+id, -e-if],[e-if, a-id]]
struct PkW7 { __half2 a, d, dn, e, en, f, fn, pad; };   // 32 B

__device__ __forceinline__ __half2 pkrtz(float lo, float hi) {
    typedef __fp16 f16x2 __attribute__((ext_vector_type(2)));
    f16x2 v = __builtin_amdgcn_cvt_pkrtz(lo, hi);
    return *reinterpret_cast<__half2*>(&v);
}
__device__ __forceinline__ unsigned h2u(__half2 v) { return *reinterpret_cast<unsigned*>(&v); }
__device__ __forceinline__ __half2 u2h(unsigned v) { return *reinterpret_cast<__half2*>(&v); }

// SoA packed butterfly: re/im in separate half2, each half2 = 2 batch states.
// Pure element-wise pk ops - no swaps, no op_sel tricks.
template<int JB>
__device__ __forceinline__ void stage16s(__half2 (&xr)[16], __half2 (&xi)[16], const PkW7 u) {
    #pragma unroll
    for (int base = 0; base < 16; ++base)
        if (!(base & (1 << JB))) {
            const int p = base | (1 << JB);
            __half2 x0r = xr[base], x0i = xi[base], x1r = xr[p], x1i = xi[p];
            xr[base] = __hfma2(u.a, x0r, __hfma2(u.dn, x0i, __hfma2(u.en, x1r, __hmul2(u.f , x1i))));
            xi[base] = __hfma2(u.a, x0i, __hfma2(u.d , x0r, __hfma2(u.en, x1i, __hmul2(u.fn, x1r))));
            xr[p]    = __hfma2(u.e, x0r, __hfma2(u.f , x0i, __hfma2(u.a , x1r, __hmul2(u.d , x1i))));
            xi[p]    = __hfma2(u.e, x0i, __hfma2(u.fn, x0r, __hfma2(u.a , x1i, __hmul2(u.dn, x1r))));
        }
}

// cbuf layout: [0..3] = wire19 f32 (a,d,e,f)*1024 ; then PkW7[20] at cbuf+4
__global__ void setupk(const float* __restrict__ params, float* __restrict__ cbuf) {
    int w = threadIdx.x;
    if (w < NW) {
        double s1, c1, s2, c2;
        sincos(0.5 * (double)params[w],      &s1, &c1);   // RX
        sincos(0.5 * (double)params[w + NW], &s2, &c2);   // RY
        float a = (float)(c1 * c2), d = (float)(s1 * s2);
        float e = (float)(s2 * c1), f = (float)(c2 * s1);
        if (w == 19) {   // first pass1 stage stays f32 and carries the x1024 scale
            cbuf[0] = a * 1024.f; cbuf[1] = d * 1024.f;
            cbuf[2] = e * 1024.f; cbuf[3] = f * 1024.f;
        }
        PkW7 pw;
        pw.a  = __floats2half2_rn( a,  a);
        pw.d  = __floats2half2_rn( d,  d);
        pw.dn = __floats2half2_rn(-d, -d);
        pw.e  = __floats2half2_rn( e,  e);
        pw.en = __floats2half2_rn(-e, -e);
        pw.f  = __floats2half2_rn( f,  f);
        pw.fn = __floats2half2_rn(-f, -f);
        pw.pad = __floats2half2_rn(0.f, 0.f);
        ((PkW7*)(cbuf + 4))[w] = pw;
    }
}

// ---------------------------------------------------------------------------
// Pass 1: wires 8..19 (y bits 0..11). Block = one 4096-amp chunk x 2 batches
// (pr, pr+16) packed in half2 lanes. Component-sequential LDS exchange:
// ONE __half2[4224] buffer reused re-then-im -> 16.9 KiB -> 8 blocks/CU.
// Skew SK(i)=i+(i>>5) folded to compile-time immediates.
// ---------------------------------------------------------------------------
__global__ __launch_bounds__(256, 8) void pass1(const float* __restrict__ state,
                                                const float* __restrict__ cbuf,
                                                uint2* __restrict__ amp) {
    __shared__ __half2 L[4224];
    const int t     = threadIdx.x;
    const int pr    = blockIdx.x >> 8;      // batch pair: (pr, pr+16)
    const int chunk = blockIdx.x & 255;
    const PkW7* PW = (const PkW7*)(cbuf + 4);
    const float a19 = cbuf[0], d19 = cbuf[1], e19 = cbuf[2], f19 = cbuf[3];

    const float4* s0 = (const float4*)(state + ((size_t)pr << 20) + ((size_t)chunk << 12));
    const float4* s1 = (const float4*)((const float*)s0 + ((size_t)16 << 20));

    __half2 xr[16], xi[16];
    // Round 1: r-bits {0,1,2,3} = i-bits {0,1,10,11} -> wires {19,18,9,8}
    // wire 19 (i-bit 0) applied in f32 on the real input, then packed.
    #pragma unroll
    for (int k = 0; k < 4; ++k) {           // i = 4t + m + 1024k (coalesced)
        float4 v0 = s0[k * 256 + t];
        float4 v1 = s1[k * 256 + t];
        float r0a = fmaf(a19, v0.x, -e19 * v0.y), i0a = fmaf( d19, v0.x, -f19 * v0.y);
        float r1a = fmaf(e19, v0.x,  a19 * v0.y), i1a = fmaf(-f19, v0.x, -d19 * v0.y);
        float r0b = fmaf(a19, v1.x, -e19 * v1.y), i0b = fmaf( d19, v1.x, -f19 * v1.y);
        float r1b = fmaf(e19, v1.x,  a19 * v1.y), i1b = fmaf(-f19, v1.x, -d19 * v1.y);
        xr[4*k+0] = pkrtz(r0a, r0b); xi[4*k+0] = pkrtz(i0a, i0b);
        xr[4*k+1] = pkrtz(r1a, r1b); xi[4*k+1] = pkrtz(i1a, i1b);
        r0a = fmaf(a19, v0.z, -e19 * v0.w); i0a = fmaf( d19, v0.z, -f19 * v0.w);
        r1a = fmaf(e19, v0.z,  a19 * v0.w); i1a = fmaf(-f19, v0.z, -d19 * v0.w);
        r0b = fmaf(a19, v1.z, -e19 * v1.w); i0b = fmaf( d19, v1.z, -f19 * v1.w);
        r1b = fmaf(e19, v1.z,  a19 * v1.w); i1b = fmaf(-f19, v1.z, -d19 * v1.w);
        xr[4*k+2] = pkrtz(r0a, r0b); xi[4*k+2] = pkrtz(i0a, i0b);
        xr[4*k+3] = pkrtz(r1a, r1b); xi[4*k+3] = pkrtz(i1a, i1b);
    }
    stage16s<1>(xr, xi, PW[18]);
    stage16s<2>(xr, xi, PW[9]);
    stage16s<3>(xr, xi, PW[8]);

    // Exchange A (component-sequential through one buffer):
    // write i = (r&3) + 4t + 1024(r>>2); SK -> p1 + (r&3) + 1056(r>>2)
    // read  i = (t&3) + 4(r&3) + 16(r>>2) + 64(t>>2); SK -> p2 + c + (c>>5)
    const int p1 = 4 * t + (t >> 3);
    const int p2 = (t & 3) + 66 * (t >> 2);
    #pragma unroll
    for (int r = 0; r < 16; ++r) L[p1 + (r & 3) + 1056 * (r >> 2)] = xr[r];
    __syncthreads();
    #pragma unroll
    for (int r = 0; r < 16; ++r) { const int c = 4 * (r & 3) + 16 * (r >> 2); xr[r] = L[p2 + c + (c >> 5)]; }
    __syncthreads();
    #pragma unroll
    for (int r = 0; r < 16; ++r) L[p1 + (r & 3) + 1056 * (r >> 2)] = xi[r];
    __syncthreads();
    #pragma unroll
    for (int r = 0; r < 16; ++r) { const int c = 4 * (r & 3) + 16 * (r >> 2); xi[r] = L[p2 + c + (c >> 5)]; }
    // each slot in the p2-pattern is read only by its owning thread -> no barrier

    // Round 2: own i-bits {2,3,4,5} -> wires {17,16,15,14}
    stage16s<0>(xr, xi, PW[17]);
    stage16s<1>(xr, xi, PW[16]);
    stage16s<2>(xr, xi, PW[15]);
    stage16s<3>(xr, xi, PW[14]);

    // Exchange B: write own p2-slots; read i = (t&63)+64(r&3)+256(r>>2)+1024(t>>6)
    const int p3 = (t & 63) + ((t & 63) >> 5) + 1056 * (t >> 6);
    #pragma unroll
    for (int r = 0; r < 16; ++r) { const int c = 4 * (r & 3) + 16 * (r >> 2); L[p2 + c + (c >> 5)] = xr[r]; }
    __syncthreads();
    #pragma unroll
    for (int r = 0; r < 16; ++r) xr[r] = L[p3 + 66 * (r & 3) + 264 * (r >> 2)];
    __syncthreads();
    #pragma unroll
    for (int r = 0; r < 16; ++r) { const int c = 4 * (r & 3) + 16 * (r >> 2); L[p2 + c + (c >> 5)] = xi[r]; }
    __syncthreads();
    #pragma unroll
    for (int r = 0; r < 16; ++r) xi[r] = L[p3 + 66 * (r & 3) + 264 * (r >> 2)];

    // Round 3: own i-bits {6,7,8,9} -> wires {13,12,11,10}
    stage16s<0>(xr, xi, PW[13]);
    stage16s<1>(xr, xi, PW[12]);
    stage16s<2>(xr, xi, PW[11]);
    stage16s<3>(xr, xi, PW[10]);

    uint2* dst = amp + ((size_t)pr << 20) + ((size_t)chunk << 12);
    const int sbase = (t & 63) + 1024 * (t >> 6);
    #pragma unroll
    for (int r = 0; r < 16; ++r) {          // lanes consecutive: 512B/wave-instr
        uint2 w; w.x = h2u(xr[r]); w.y = h2u(xi[r]);
        dst[sbase + 64 * (r & 3) + 256 * (r >> 2)] = w;
    }
}

// ---------------------------------------------------------------------------
// Pass 2: wires 0..7 (y bits 12..19), SoA pk stages, + fused |psi|^2 * g(y).
// g(y) = A(h) + sigma(h)*B(low); two batches per block (packed lanes).
// Component-sequential LDS exchange -> ~19.3 KiB -> 8 blocks/CU.
// Loads: 16 consecutive lanes = 128 B contiguous (L3-hot intermediate).
// ---------------------------------------------------------------------------
__global__ __launch_bounds__(256, 8) void pass2(const uint2* __restrict__ amp,
                                                const float* __restrict__ cbuf,
                                                const float* __restrict__ Wv,
                                                float* __restrict__ pws) {
    __shared__ __half2 L[4224];
    __shared__ float2  Asig[256];
    __shared__ float   Btab[16];
    __shared__ float   wred[8];
    const int t        = threadIdx.x;
    const int pr       = blockIdx.x >> 8;
    const int chunk    = blockIdx.x & 255;
    const int low_base = chunk * 16;
    const int l = t & 15, hi = t >> 4;
    const PkW7* PW = (const PkW7*)(cbuf + 4);

    {   // A(h) = sum_{i<8} W_i * (-1)^{parity(h>>(7-i))}, sigma(h) = (-1)^{parity(h)}
        float A = 0.f;
        #pragma unroll
        for (int i = 0; i < 8; ++i)
            A += Wv[i] * (1.f - 2.f * (float)(__popc(t >> (7 - i)) & 1));
        Asig[t] = make_float2(A, 1.f - 2.f * (float)(__popc(t) & 1));
    }
    if (t < 16) {   // B(low) = sum_{i=8..19} W_i * (-1)^{parity(low>>(19-i))}
        int low = low_base + t;
        float Bs = 0.f;
        #pragma unroll
        for (int i = 8; i < 20; ++i)
            Bs += Wv[i] * (1.f - 2.f * (float)(__popc(low >> (19 - i)) & 1));
        Btab[t] = Bs;
    }

    const uint2* src = amp + ((size_t)pr << 20) + low_base + l;
    __half2 xr[16], xi[16];
    #pragma unroll
    for (int r = 0; r < 16; ++r) {          // 128B-contiguous per 16 lanes
        uint2 w = src[(size_t)(hi * 16 + r) * 4096];
        xr[r] = u2h(w.x); xi[r] = u2h(w.y);
    }
    // Round 1: h-bits 0..3 -> wires 7,6,5,4
    stage16s<0>(xr, xi, PW[7]);
    stage16s<1>(xr, xi, PW[6]);
    stage16s<2>(xr, xi, PW[5]);
    stage16s<3>(xr, xi, PW[4]);

    // Exchange (component-sequential): write i = 264*hi + l + 16r + (r>>1);
    // read i = r*256 + t; SK -> (t + (t>>5)) + 264r
    const int p = 264 * hi + l;
    const int q = t + (t >> 5);
    #pragma unroll
    for (int r = 0; r < 16; ++r) L[p + 16 * r + (r >> 1)] = xr[r];
    __syncthreads();                        // also covers Asig/Btab visibility
    #pragma unroll
    for (int r = 0; r < 16; ++r) xr[r] = L[q + 264 * r];
    __syncthreads();
    #pragma unroll
    for (int r = 0; r < 16; ++r) L[p + 16 * r + (r >> 1)] = xi[r];
    __syncthreads();
    #pragma unroll
    for (int r = 0; r < 16; ++r) xi[r] = L[q + 264 * r];

    // Round 2: h-bits 4..7 -> wires 3,2,1,0
    stage16s<0>(xr, xi, PW[3]);
    stage16s<1>(xr, xi, PW[2]);
    stage16s<2>(xr, xi, PW[1]);
    stage16s<3>(xr, xi, PW[0]);

    // fused weighted-probability accumulation (h = r*16 + hi), f32 epilogue
    const float Bl = Btab[l];
    float acc0 = 0.f, acc1 = 0.f;
    #pragma unroll
    for (int r = 0; r < 16; ++r) {
        float2 vr = __half22float2(xr[r]);
        float2 vi = __half22float2(xi[r]);
        float2 as = Asig[r * 16 + hi];
        float g = fmaf(as.y, Bl, as.x);
        acc0 = fmaf(fmaf(vr.x, vr.x, vi.x * vi.x), g, acc0);
        acc1 = fmaf(fmaf(vr.y, vr.y, vi.y * vi.y), g, acc1);
    }
    #pragma unroll
    for (int off = 32; off > 0; off >>= 1) {
        acc0 += __shfl_down(acc0, off, 64);
        acc1 += __shfl_down(acc1, off, 64);
    }
    if ((t & 63) == 0) { wred[(t >> 6) * 2] = acc0; wred[(t >> 6) * 2 + 1] = acc1; }
    __syncthreads();
    if (t < 2)
        pws[blockIdx.x * 2 + t] = (wred[t] + wred[2 + t]) + (wred[4 + t] + wred[6 + t]);
}

// ---------------------------------------------------------------------------
// Final: deterministic reduction of 256 partials per batch, undo 2^20 scale.
// Batch b lives in pair pr=b&15, slot sl=b>>4.
// ---------------------------------------------------------------------------
__global__ void finalk(const float* __restrict__ pws, const float* __restrict__ bias,
                       float* __restrict__ out) {
    const int t = threadIdx.x;
    const int b = t >> 3, j = t & 7;
    const int pr = b & 15, sl = b >> 4;
    float s = 0.f;
    #pragma unroll 4
    for (int k = 0; k < 32; ++k) {
        const int c = j * 32 + k;
        s += pws[(pr * 256 + c) * 2 + sl];
    }
    s += __shfl_down(s, 4, 8);
    s += __shfl_down(s, 2, 8);
    s += __shfl_down(s, 1, 8);
    if (j == 0) out[b] = s * (1.f / 1048576.f) + bias[0];
}

extern "C" void kernel_launch(void* const* d_in, const int* in_sizes, int n_in,
                              void* d_out, int out_size, void* d_ws, size_t ws_size,
                              hipStream_t stream) {
    const float* state  = (const float*)d_in[0];   // (32, 2^20) f32
    const float* params = (const float*)d_in[1];   // (40,) f32
    const float* Wv     = (const float*)d_in[2];   // (1,20) f32
    const float* bias   = (const float*)d_in[3];   // (1,)  f32
    float* out = (float*)d_out;                    // (32,) f32

    const size_t AMPB = (size_t)16 * (1u << 20) * 8;   // 128 MiB intermediate
    uint2* amp  = (uint2*)d_ws;
    float* pws  = (float*)((char*)d_ws + AMPB);        // 16*256*2 floats
    float* cbuf = (float*)((char*)d_ws + AMPB + 65536);

    setupk<<<1, 64, 0, stream>>>(params, cbuf);
    pass1 <<<16 * 256, 256, 0, stream>>>(state, cbuf, amp);
    pass2 <<<16 * 256, 256, 0, stream>>>(amp, cbuf, Wv, pws);
    finalk<<<1, 256, 0, stream>>>(pws, bias, out);
}